// Round 3
// baseline (43.127 us; speedup 1.0000x reference)
//
#include <hip/hip_runtime.h>
#include <cmath>

constexpr int Bn = 2, Hn = 256, Wn = 256, Cn = 2;
constexpr int NG = 16;   // i-groups (each covers 16 i's)
constexpr int NJ = 4;    // j's per thread: jl + {0,64,128,192}

__global__ __launch_bounds__(1024, 8) void sinc_warp_kernel(
    const float* __restrict__ img, const float* __restrict__ fmap,
    float* __restrict__ out)
{
    const float INV_PI = 0x1.45f306p-2f;  // float32(1/pi)
    // d==0 guard: x0 integer there => sin term exactly 0 => p==0, and
    // rcp(1e-37)=1e37 is finite, so the term contributes exactly 0.
    // (Ref's TF quirk value is +-2.8e-8*img ~ 1e-7, far below threshold.)
    // For d!=0, |d| >= ~6e-8 so adding 1e-37 leaves d bit-identical.
    const float BIAS = 1e-37f;

    __shared__ __align__(16) float sh_x[Hn * Cn];   // x0, packed [i][c]
    __shared__ __align__(16) float sh_p[Hn * Cn];   // img * sin(pi*x0)/pi
    __shared__ float sh_acc[NG][Hn * Cn];           // 32 KB partials

    const int bw = blockIdx.x;
    const int b  = bw >> 8;   // / Wn
    const int w  = bw & 255;  // % Wn
    const int t  = threadIdx.x;

    // Stage: thread t < 512 owns (i = t>>1, c = t&1).
    if (t < Hn * Cn) {
        const int i = t >> 1, c = t & 1;
        const size_t base = (((size_t)b * Hn + i) * Wn + w) * Cn + c;
        const float f  = fmap[base];
        float x0 = fminf(fmaxf(f + (float)i, 0.0f), 255.0f);
        const float n = rintf(x0);          // x0 >= 0
        const float r = x0 - n;             // r in [-0.5, 0.5]
        // sin(pi*r) via v_sin_f32 (revolutions): sin(2*pi*(r/2))
        float sp = __builtin_amdgcn_sinf(0.5f * r) * INV_PI;
        if (((int)n) & 1) sp = -sp;         // sp = sin(pi*x0)/pi
        sh_x[t] = x0;
        sh_p[t] = img[base] * sp;
    }
    __syncthreads();

    // Compute: thread (ig, jl) sums i in [ig*16, ig*16+16) for
    // j in {jl, jl+64, jl+128, jl+192}, both channels.
    // (-1)^j folded out of the loop; applied at the final store.
    const int ig = t >> 6;
    const int jl = t & 63;

    float acc[NJ][2];
#pragma unroll
    for (int jj = 0; jj < NJ; ++jj) { acc[jj][0] = 0.0f; acc[jj][1] = 0.0f; }

    const float4* px = (const float4*)sh_x;
    const float4* pp = (const float4*)sh_p;
    const int k0 = ig * 8;   // 16 i's = 8 float4 groups (2 i x 2 c each)

#pragma unroll
    for (int k = 0; k < 8; ++k) {
        const float4 xv = px[k0 + k];
        const float4 pv = pp[k0 + k];
#pragma unroll
        for (int jj = 0; jj < NJ; ++jj) {
            const float J = (float)(jl + 64 * jj);
            acc[jj][0] = fmaf(pv.x, __builtin_amdgcn_rcpf((xv.x - J) + BIAS), acc[jj][0]);
            acc[jj][1] = fmaf(pv.y, __builtin_amdgcn_rcpf((xv.y - J) + BIAS), acc[jj][1]);
            acc[jj][0] = fmaf(pv.z, __builtin_amdgcn_rcpf((xv.z - J) + BIAS), acc[jj][0]);
            acc[jj][1] = fmaf(pv.w, __builtin_amdgcn_rcpf((xv.w - J) + BIAS), acc[jj][1]);
        }
    }

    // Partials -> LDS, reduce across the 16 i-groups.
#pragma unroll
    for (int jj = 0; jj < NJ; ++jj) {
        const int j = jl + 64 * jj;
        *(float2*)&sh_acc[ig][j * 2] = make_float2(acc[jj][0], acc[jj][1]);
    }
    __syncthreads();

    if (t < Hn * Cn) {
        float a = 0.0f;
#pragma unroll
        for (int g = 0; g < NG; ++g) a += sh_acc[g][t];
        const int j = t >> 1, c = t & 1;
        const float sgn = (j & 1) ? -1.0f : 1.0f;
        out[(((size_t)b * Hn + j) * Wn + w) * Cn + c] = sgn * a;
    }
}

extern "C" void kernel_launch(void* const* d_in, const int* in_sizes, int n_in,
                              void* d_out, int out_size, void* d_ws, size_t ws_size,
                              hipStream_t stream)
{
    (void)in_sizes; (void)n_in; (void)out_size; (void)d_ws; (void)ws_size;
    const float* img  = (const float*)d_in[0];
    const float* fmap = (const float*)d_in[1];
    float* out = (float*)d_out;
    sinc_warp_kernel<<<Bn * Wn, 1024, 0, stream>>>(img, fmap, out);
}

// Round 4
// 18.220 us; speedup vs baseline: 2.3670x; 2.3670x over previous
//
#include <hip/hip_runtime.h>
#include <cmath>

constexpr int Bn = 2, Hn = 256, Wn = 256, Cn = 2;
constexpr int NG = 16;   // i-groups (each covers 16 i's)
constexpr int NJ = 4;    // j's per thread: jl + {0,64,128,192}

__global__ __launch_bounds__(1024, 4) void sinc_warp_kernel(
    const float* __restrict__ img, const float* __restrict__ fmap,
    float* __restrict__ out)
{
    const float INV_PI = 0x1.45f306p-2f;  // float32(1/pi)
    // d==0 guard: x0 integer there => sin term exactly 0 => p==0, and
    // rcp(1e-37)=1e37 is finite, so the term contributes exactly 0.
    // (Ref's TF quirk value is +-2.8e-8*img ~ 1e-7, far below threshold.)
    // For d!=0, |d| >= ~6e-8 so adding 1e-37 leaves d bit-identical.
    const float BIAS = 1e-37f;

    __shared__ __align__(16) float sh_x[Hn * Cn];   // x0, packed [i][c]
    __shared__ __align__(16) float sh_p[Hn * Cn];   // img * sin(pi*x0)/pi
    __shared__ float sh_acc[NG][Hn * Cn];           // 32 KB partials

    const int bw = blockIdx.x;
    const int b  = bw >> 8;   // / Wn
    const int w  = bw & 255;  // % Wn
    const int t  = threadIdx.x;

    // Stage: thread t < 512 owns (i = t>>1, c = t&1).
    if (t < Hn * Cn) {
        const int i = t >> 1, c = t & 1;
        const size_t base = (((size_t)b * Hn + i) * Wn + w) * Cn + c;
        const float f  = fmap[base];
        float x0 = fminf(fmaxf(f + (float)i, 0.0f), 255.0f);
        const float n = rintf(x0);          // x0 >= 0
        const float r = x0 - n;             // r in [-0.5, 0.5]
        // sin(pi*r) via v_sin_f32 (revolutions): sin(2*pi*(r/2))
        float sp = __builtin_amdgcn_sinf(0.5f * r) * INV_PI;
        if (((int)n) & 1) sp = -sp;         // sp = sin(pi*x0)/pi
        sh_x[t] = x0;
        sh_p[t] = img[base] * sp;
    }
    __syncthreads();

    // Compute: thread (ig, jl) sums i in [ig*16, ig*16+16) for
    // j in {jl, jl+64, jl+128, jl+192}, both channels.
    // (-1)^j folded out of the loop; applied at the final store.
    const int ig = t >> 6;
    const int jl = t & 63;

    float acc[NJ][2];
#pragma unroll
    for (int jj = 0; jj < NJ; ++jj) { acc[jj][0] = 0.0f; acc[jj][1] = 0.0f; }

    const float4* px = (const float4*)sh_x;
    const float4* pp = (const float4*)sh_p;
    const int k0 = ig * 8;   // 16 i's = 8 float4 groups (2 i x 2 c each)

#pragma unroll
    for (int k = 0; k < 8; ++k) {
        const float4 xv = px[k0 + k];
        const float4 pv = pp[k0 + k];
#pragma unroll
        for (int jj = 0; jj < NJ; ++jj) {
            const float J = (float)(jl + 64 * jj);
            acc[jj][0] = fmaf(pv.x, __builtin_amdgcn_rcpf((xv.x - J) + BIAS), acc[jj][0]);
            acc[jj][1] = fmaf(pv.y, __builtin_amdgcn_rcpf((xv.y - J) + BIAS), acc[jj][1]);
            acc[jj][0] = fmaf(pv.z, __builtin_amdgcn_rcpf((xv.z - J) + BIAS), acc[jj][0]);
            acc[jj][1] = fmaf(pv.w, __builtin_amdgcn_rcpf((xv.w - J) + BIAS), acc[jj][1]);
        }
    }

    // Partials -> LDS, reduce across the 16 i-groups.
#pragma unroll
    for (int jj = 0; jj < NJ; ++jj) {
        const int j = jl + 64 * jj;
        *(float2*)&sh_acc[ig][j * 2] = make_float2(acc[jj][0], acc[jj][1]);
    }
    __syncthreads();

    if (t < Hn * Cn) {
        float a = 0.0f;
#pragma unroll
        for (int g = 0; g < NG; ++g) a += sh_acc[g][t];
        const int j = t >> 1, c = t & 1;
        const float sgn = (j & 1) ? -1.0f : 1.0f;
        out[(((size_t)b * Hn + j) * Wn + w) * Cn + c] = sgn * a;
    }
}

extern "C" void kernel_launch(void* const* d_in, const int* in_sizes, int n_in,
                              void* d_out, int out_size, void* d_ws, size_t ws_size,
                              hipStream_t stream)
{
    (void)in_sizes; (void)n_in; (void)out_size; (void)d_ws; (void)ws_size;
    const float* img  = (const float*)d_in[0];
    const float* fmap = (const float*)d_in[1];
    float* out = (float*)d_out;
    sinc_warp_kernel<<<Bn * Wn, 1024, 0, stream>>>(img, fmap, out);
}

// Round 5
// 18.149 us; speedup vs baseline: 2.3762x; 1.0039x over previous
//
#include <hip/hip_runtime.h>
#include <cmath>

constexpr int Bn = 2, Hn = 256, Wn = 256, Cn = 2;
constexpr int NG = 16;   // i-groups (each covers 16 i's)
constexpr int NJ = 4;    // j's per thread: jl + {0,64,128,192}

__global__ __launch_bounds__(1024, 4) void sinc_warp_kernel(
    const float* __restrict__ img, const float* __restrict__ fmap,
    float* __restrict__ out)
{
    const float INV_PI = 0x1.45f306p-2f;  // float32(1/pi)
    // Grouped-reciprocal zero guard. d==0 only where x0 is an exact integer,
    // and there sin(pi*x0)==+-0 => p==0, so the term must contribute 0.
    // BIAS=2^-31 keeps a worst-case 4-zero group product at (2^-31)^4=4.7e-38
    // (still normal => rcp finite => 0*finite = 0). Legit |d|>=~6e-8 is
    // perturbed <=0.8% => abs error <=~0.04, far under the 0.1325 threshold.
    const float BIAS = 0x1p-31f;

    __shared__ __align__(16) float sh_x[Hn * Cn];   // x0, packed [i][c]
    __shared__ __align__(16) float sh_p[Hn * Cn];   // img * sin(pi*x0)/pi
    __shared__ float sh_acc[NG][Hn * Cn];           // 32 KB partials

    const int bw = blockIdx.x;
    const int b  = bw >> 8;   // / Wn
    const int w  = bw & 255;  // % Wn
    const int t  = threadIdx.x;

    // Stage: thread t < 512 owns (i = t>>1, c = t&1).
    if (t < Hn * Cn) {
        const int i = t >> 1, c = t & 1;
        const size_t base = (((size_t)b * Hn + i) * Wn + w) * Cn + c;
        const float f  = fmap[base];
        float x0 = fminf(fmaxf(f + (float)i, 0.0f), 255.0f);
        const float n = rintf(x0);          // x0 >= 0
        const float r = x0 - n;             // r in [-0.5, 0.5]
        // sin(pi*r) via v_sin_f32 (revolutions): sin(2*pi*(r/2))
        float sp = __builtin_amdgcn_sinf(0.5f * r) * INV_PI;
        if (((int)n) & 1) sp = -sp;         // sp = sin(pi*x0)/pi
        sh_x[t] = x0;
        sh_p[t] = img[base] * sp;
    }
    __syncthreads();

    // Compute: thread (ig, jl) sums i in [ig*16, ig*16+16) for
    // j in {jl, jl+64, jl+128, jl+192}, both channels.
    // (-1)^j folded out of the loop; applied at the final store.
    const int ig = t >> 6;
    const int jl = t & 63;

    float acc[NJ][2];
#pragma unroll
    for (int jj = 0; jj < NJ; ++jj) { acc[jj][0] = 0.0f; acc[jj][1] = 0.0f; }

    const float4* px = (const float4*)sh_x;
    const float4* pp = (const float4*)sh_p;
    const int k0 = ig * 8;   // 16 i's = 8 float4 groups (2 i x 2 c each)

#pragma unroll
    for (int k = 0; k < 8; ++k) {
        const float4 xv = px[k0 + k];
        const float4 pv = pp[k0 + k];
#pragma unroll
        for (int jj = 0; jj < NJ; ++jj) {
            const float J = (float)(jl + 64 * jj);
            // One v_rcp_f32 serves 4 terms: 1/(d0 d1) and 1/(d2 d3) are
            // recovered from rcp(d0 d1 d2 d3) by multiplication.
            const float d0 = (xv.x - J) + BIAS;
            const float d1 = (xv.y - J) + BIAS;
            const float d2 = (xv.z - J) + BIAS;
            const float d3 = (xv.w - J) + BIAS;
            const float m01 = d0 * d1;
            const float m23 = d2 * d3;
            const float r   = __builtin_amdgcn_rcpf(m01 * m23);
            const float r01 = m23 * r;   // = 1/(d0*d1)
            const float r23 = m01 * r;   // = 1/(d2*d3)
            acc[jj][0] = fmaf(pv.x, d1 * r01, acc[jj][0]);
            acc[jj][1] = fmaf(pv.y, d0 * r01, acc[jj][1]);
            acc[jj][0] = fmaf(pv.z, d3 * r23, acc[jj][0]);
            acc[jj][1] = fmaf(pv.w, d2 * r23, acc[jj][1]);
        }
    }

    // Partials -> LDS, reduce across the 16 i-groups.
#pragma unroll
    for (int jj = 0; jj < NJ; ++jj) {
        const int j = jl + 64 * jj;
        *(float2*)&sh_acc[ig][j * 2] = make_float2(acc[jj][0], acc[jj][1]);
    }
    __syncthreads();

    if (t < Hn * Cn) {
        float a = 0.0f;
#pragma unroll
        for (int g = 0; g < NG; ++g) a += sh_acc[g][t];
        const int j = t >> 1, c = t & 1;
        const float sgn = (j & 1) ? -1.0f : 1.0f;
        out[(((size_t)b * Hn + j) * Wn + w) * Cn + c] = sgn * a;
    }
}

extern "C" void kernel_launch(void* const* d_in, const int* in_sizes, int n_in,
                              void* d_out, int out_size, void* d_ws, size_t ws_size,
                              hipStream_t stream)
{
    (void)in_sizes; (void)n_in; (void)out_size; (void)d_ws; (void)ws_size;
    const float* img  = (const float*)d_in[0];
    const float* fmap = (const float*)d_in[1];
    float* out = (float*)d_out;
    sinc_warp_kernel<<<Bn * Wn, 1024, 0, stream>>>(img, fmap, out);
}